// Round 6
// baseline (537.528 us; speedup 1.0000x reference)
//
#include <hip/hip_runtime.h>
#include <hip/hip_fp16.h>
#include <math.h>

// ---------------------------------------------------------------------------
// TensorFieldNetwork on MI355X — round 6.
// Round-5 PMC: full_layer 186us, VALUBusy 52%, occ 38% (grid-capped 3 blocks/CU
// of 512thr), HBM 1% -> load-latency bound, not enough waves.
// This round: split-K over neighbors (2 blocks/atom x 256thr, partials to
// global + tiny finish kernels) -> 8 blocks/CU, 100% occupancy headroom;
// q/fr/table-offset hoisted to pair setup (LDS); x packed fp16 [N][C][4]
// (1 dwordx2/pair). Table fp16 {val,delta}, M=320 over [0,6.4] w/ exact
// asymptotic clamp; table+x = 2.7MB fits XCD L2.
// ---------------------------------------------------------------------------

constexpr int   N_    = 768;
constexpr int   C_    = 128;
constexpr int   M_    = 320;
constexpr float DMAX_ = 6.4f;
constexpr float GAMMA_ = 1.6f;     // RBF / (HIGH - LOW)

// ---------------------------------------------------------------------------
// Kernel A: build radial tables, fp16 {val, delta} packed in __half2.
// Layout tab[(m*12 + filter)*C + f]. grid = M/4 x 256 thr.
// ---------------------------------------------------------------------------
__global__ __launch_bounds__(256) void build_table_kernel(
    const float* __restrict__ Rw1, const float* __restrict__ Rb1,
    const float* __restrict__ Rw2, const float* __restrict__ Rb2,
    __half2* __restrict__ tab, float delta)
{
    const int f  = threadIdx.x & 127, fh = threadIdx.x >> 7;
    const int m0 = blockIdx.x * 4;

    __shared__ float hs[2][5][C_];

    float rbf[5][4];
    const float cent[4] = {0.0f, 2.5f / 3.0f, 5.0f / 3.0f, 2.5f};
#pragma unroll
    for (int mm = 0; mm < 5; ++mm) {
        int m = m0 + mm; if (m > M_ - 1) m = M_ - 1;
        const float d = (float)m * delta;
#pragma unroll
        for (int k = 0; k < 4; ++k) {
            const float t = d - cent[k];
            rbf[mm][k] = expf(-GAMMA_ * t * t);
        }
    }

    for (int ii = 0; ii < 6; ++ii) {
        const int i = fh * 6 + ii;
        float w1v[4];
#pragma unroll
        for (int k = 0; k < 4; ++k) w1v[k] = Rw1[(i * 4 + k) * C_ + f];
        const float b1v = Rb1[i * C_ + f];

        __syncthreads();               // previous iteration's readers done
#pragma unroll
        for (int mm = 0; mm < 5; ++mm) {
            float acc = b1v;
#pragma unroll
            for (int k = 0; k < 4; ++k) acc = fmaf(rbf[mm][k], w1v[k], acc);
            hs[fh][mm][f] = fmaxf(acc, 0.0f);
        }
        __syncthreads();

        const float b2v = Rb2[i * C_ + f];
        float out[5] = {b2v, b2v, b2v, b2v, b2v};
        for (int c = 0; c < C_; ++c) {
            const float w = Rw2[(i * C_ + c) * C_ + f];
#pragma unroll
            for (int mm = 0; mm < 5; ++mm) out[mm] = fmaf(hs[fh][mm][c], w, out[mm]);
        }
#pragma unroll
        for (int mm = 0; mm < 4; ++mm) {
            const int m = m0 + mm;
            if (m < M_)
                tab[((size_t)m * 12 + i) * C_ + f] =
                    __floats2half2_rn(out[mm], out[mm + 1] - out[mm]);
        }
    }
}

// ---------------------------------------------------------------------------
// Kernel B: embedding  e[b,f] = one_hot[b,:] @ embed_W[f,:] + embed_b[f]
// ---------------------------------------------------------------------------
__global__ __launch_bounds__(256) void embed_kernel(
    const float* __restrict__ onehot, const float* __restrict__ eW,
    const float* __restrict__ eb, float* __restrict__ e)
{
    const int idx = blockIdx.x * 256 + threadIdx.x;
    const int b = idx >> 7, f = idx & 127;
    float acc = eb[f];
#pragma unroll
    for (int t = 0; t < 8; ++t) acc = fmaf(onehot[b * 8 + t], eW[f * 8 + t], acc);
    e[idx] = acc;
}

// ---------------------------------------------------------------------------
// Shared pair-setup: compute {u, fr} and table offset for 384 neighbors.
// ---------------------------------------------------------------------------
template <int RI>
__device__ inline void pair_setup(const float* __restrict__ r, int a, int bbase,
                                  int tid, float4* pair, int* qoff)
{
    const float rax = r[a * 3 + 0], ray = r[a * 3 + 1], raz = r[a * 3 + 2];
    for (int i = tid; i < 384; i += 256) {
        const int b = bbase + i;
        const float dx = rax - r[b * 3 + 0];
        const float dy = ray - r[b * 3 + 1];
        const float dz = raz - r[b * 3 + 2];
        const float d2 = fmaf(dx, dx, fmaf(dy, dy, dz * dz));
        const float d  = sqrtf(fmaxf(d2, 1e-12f));
        const float inv = 1.0f / (d + 1e-8f);
        const float t = d * ((float)(M_ - 1) / DMAX_);
        int q = (int)t; q = q > M_ - 2 ? M_ - 2 : q;
        const float fr = fminf(t - (float)q, 1.0f);
        pair[i] = make_float4(dx * inv, dy * inv, dz * inv, fr);
        qoff[i] = (q * 12 + RI) * C_;
    }
}

// ---------------------------------------------------------------------------
// Kernel C1: layer-0 pair phase. grid = 2*N blocks x 256 thr.
// block = (atom a, b-half p). parts: tid>>7 in {0,1}, 192 pairs each.
// Writes partial sums P0[p][a][4][C].
// ---------------------------------------------------------------------------
__global__ __launch_bounds__(256, 8) void pair0_kernel(
    const float* __restrict__ r, const float* __restrict__ e,
    const __half2* __restrict__ tab, float* __restrict__ P)
{
    const int a = blockIdx.x >> 1, p = blockIdx.x & 1;
    const int tid = threadIdx.x;
    const int f = tid & 127, part = tid >> 7;
    const int bbase = p * 384;

    __shared__ float4 pair[384];
    __shared__ int    qoff[384];
    __shared__ float  sred[4][2][C_];

    pair_setup<0>(r, a, bbase, tid, pair, qoff);
    __syncthreads();

    float c00 = 0.f, cx = 0.f, cy = 0.f, cz = 0.f;
    const __half2* tabf = tab + f;
    const int iBeg = part * 192, iEnd = iBeg + 192;
    for (int i = iBeg; i < iEnd; ++i) {
        const float4 pr = pair[i];
        const __half2* tp = tabf + qoff[i];
        const __half2 h0 = tp[0], h1 = tp[C_];
        const float eb_ = e[(bbase + i) * C_ + f];
        const float fr = pr.w;
        const float2 v0 = __half22float2(h0);
        const float2 v1 = __half22float2(h1);
        const float t0 = fmaf(fr, v0.y, v0.x);
        const float t1 = fmaf(fr, v1.y, v1.x);
        c00 = fmaf(t0, eb_, c00);
        const float te = t1 * eb_;
        cx = fmaf(te, pr.x, cx); cy = fmaf(te, pr.y, cy); cz = fmaf(te, pr.z, cz);
    }

    sred[0][part][f] = c00;
    sred[1][part][f] = cx;
    sred[2][part][f] = cy;
    sred[3][part][f] = cz;
    __syncthreads();

    for (int idx = tid; idx < 4 * C_; idx += 256) {
        const int k = idx >> 7, c = idx & 127;
        P[((size_t)(p * N_ + a) * 4 + k) * C_ + c] =
            sred[k][0][c] + sred[k][1][c];
    }
}

// ---------------------------------------------------------------------------
// Kernel C2: full-layer pair phase (RI = 2 or 7). grid = 2*N x 256 thr.
// Reads x packed fp16 [N][C][4] (uint2), writes P[p][a][11][C].
// ---------------------------------------------------------------------------
template <int RI>
__global__ __launch_bounds__(256, 8) void pairF_kernel(
    const float* __restrict__ r, const uint2* __restrict__ xin,
    const __half2* __restrict__ tab, float* __restrict__ P)
{
    const int a = blockIdx.x >> 1, p = blockIdx.x & 1;
    const int tid = threadIdx.x;
    const int f = tid & 127, part = tid >> 7;
    const int bbase = p * 384;

    __shared__ float4 pair[384];
    __shared__ int    qoff[384];
    __shared__ float  sred[11][2][C_];

    pair_setup<RI>(r, a, bbase, tid, pair, qoff);
    __syncthreads();

    float a0 = 0.f, b1x = 0.f, b1y = 0.f, b1z = 0.f;
    float a1x = 0.f, a1y = 0.f, a1z = 0.f;
    float o0 = 0.f, o1x = 0.f, o1y = 0.f, o1z = 0.f;

    const __half2* tabf = tab + f;
    const uint2*   xf   = xin + (size_t)bbase * C_ + f;
    const int iBeg = part * 192, iEnd = iBeg + 192;
    for (int i = iBeg; i < iEnd; ++i) {
        const float4 pr = pair[i];
        const __half2* tp = tabf + qoff[i];
        const __half2 h0 = tp[0 * C_], h1 = tp[1 * C_], h2 = tp[2 * C_];
        const __half2 h3 = tp[3 * C_], h4 = tp[4 * C_];
        const uint2 xw = xf[(size_t)i * C_];

        const float fr = pr.w;
        const float2 v0 = __half22float2(h0);
        const float2 v1 = __half22float2(h1);
        const float2 v2 = __half22float2(h2);
        const float2 v3 = __half22float2(h3);
        const float2 v4 = __half22float2(h4);
        const float t0 = fmaf(fr, v0.y, v0.x);
        const float t1 = fmaf(fr, v1.y, v1.x);
        const float t2 = fmaf(fr, v2.y, v2.x);
        const float t3 = fmaf(fr, v3.y, v3.x);
        const float t4 = fmaf(fr, v4.y, v4.x);

        const float2 x01 = __half22float2(*(const __half2*)&xw.x);
        const float2 x23 = __half22float2(*(const __half2*)&xw.y);
        const float x0b = x01.x, xbx = x01.y, xby = x23.x, xbz = x23.y;

        a0 = fmaf(t0, x0b, a0);
        const float tb = t1 * x0b;
        b1x = fmaf(tb, pr.x, b1x); b1y = fmaf(tb, pr.y, b1y); b1z = fmaf(tb, pr.z, b1z);
        a1x = fmaf(t2, xbx, a1x); a1y = fmaf(t2, xby, a1y); a1z = fmaf(t2, xbz, a1z);
        const float ud = fmaf(pr.x, xbx, fmaf(pr.y, xby, pr.z * xbz));
        o0 = fmaf(t3, ud, o0);
        const float crx = pr.y * xbz - pr.z * xby;
        const float cry = pr.z * xbx - pr.x * xbz;
        const float crz = pr.x * xby - pr.y * xbx;
        o1x = fmaf(t4, crx, o1x); o1y = fmaf(t4, cry, o1y); o1z = fmaf(t4, crz, o1z);
    }

    sred[0][part][f] = a0;
    sred[1][part][f] = b1x; sred[2][part][f] = b1y; sred[3][part][f] = b1z;
    sred[4][part][f] = a1x; sred[5][part][f] = a1y; sred[6][part][f] = a1z;
    sred[7][part][f] = o0;
    sred[8][part][f] = o1x; sred[9][part][f] = o1y; sred[10][part][f] = o1z;
    __syncthreads();

    for (int idx = tid; idx < 11 * C_; idx += 256) {
        const int k = idx >> 7, c = idx & 127;
        P[((size_t)(p * N_ + a) * 11 + k) * C_ + c] =
            sred[k][0][c] + sred[k][1][c];
    }
}

// ---------------------------------------------------------------------------
// Kernel D1: layer-0 finish. grid = N x 512 thr.
// Reduce P0 partials, SI (w0 CxC on s0, w1 CxC on s1..3), ELU/gate, write
// x packed fp16 [N][C][4].
// ---------------------------------------------------------------------------
__global__ __launch_bounds__(512) void finish0_kernel(
    const float* __restrict__ P,
    const float* __restrict__ w0, const float* __restrict__ b0v,
    const float* __restrict__ w1, const float* __restrict__ nlb,
    uint2* __restrict__ xout)
{
    const int a = blockIdx.x, tid = threadIdx.x;
    const int f = tid & 127;

    __shared__ float s[4 * C_];
    __shared__ float ys[4 * C_];

    for (int idx = tid; idx < 4 * C_; idx += 512)
        s[idx] = P[(size_t)a * 4 * C_ + idx] +
                 P[((size_t)(N_ + a) * 4) * C_ + idx];
    __syncthreads();

    {
        const int j = tid >> 7;
        float y;
        if (j == 0) {
            y = b0v[f];
            const float4* w = (const float4*)(w0 + (size_t)f * C_);
            for (int c4 = 0; c4 < C_ / 4; ++c4) {
                const float4 wv = w[c4];
                y = fmaf(wv.x, s[c4 * 4 + 0], y);
                y = fmaf(wv.y, s[c4 * 4 + 1], y);
                y = fmaf(wv.z, s[c4 * 4 + 2], y);
                y = fmaf(wv.w, s[c4 * 4 + 3], y);
            }
        } else {
            y = 0.f;
            const float4* w = (const float4*)(w1 + (size_t)f * C_);
            const float* sj = s + j * C_;
            for (int c4 = 0; c4 < C_ / 4; ++c4) {
                const float4 wv = w[c4];
                y = fmaf(wv.x, sj[c4 * 4 + 0], y);
                y = fmaf(wv.y, sj[c4 * 4 + 1], y);
                y = fmaf(wv.z, sj[c4 * 4 + 2], y);
                y = fmaf(wv.w, sj[c4 * 4 + 3], y);
            }
        }
        ys[j * C_ + f] = y;
    }
    __syncthreads();

    if (tid < C_) {
        const float y0 = ys[tid];
        const float yx = ys[C_ + tid], yy = ys[2 * C_ + tid], yz = ys[3 * C_ + tid];
        const float x0v = y0 > 0.f ? y0 : expm1f(y0);
        const float nsq = fmaf(yx, yx, fmaf(yy, yy, yz * yz));
        const float nn  = sqrtf(fmaxf(nsq, 1e-12f));
        const float g   = nlb[tid] + nn;
        const float sc  = (g > 0.f ? g : expm1f(g)) / nn;
        uint2 w;
        *(__half2*)&w.x = __floats2half2_rn(x0v, yx * sc);
        *(__half2*)&w.y = __floats2half2_rn(yy * sc, yz * sc);
        xout[(size_t)a * C_ + tid] = w;
    }
}

// ---------------------------------------------------------------------------
// Kernel D2: full-layer finish. grid = N x 512 thr.
// Reduce P partials (11 k's), SI (w0 Cx2C, w1 Cx3C), optional nonlin ->
// x fp16; LAST -> final outputs + atom head.
// ---------------------------------------------------------------------------
template <bool NONLIN, bool LAST>
__global__ __launch_bounds__(512) void finishF_kernel(
    const float* __restrict__ P,
    const float* __restrict__ w0, const float* __restrict__ b0v,
    const float* __restrict__ w1, const float* __restrict__ nlb,
    uint2* __restrict__ xout,
    float* __restrict__ out, const float* __restrict__ predW,
    const float* __restrict__ predb)
{
    const int a = blockIdx.x, tid = threadIdx.x;
    const int f = tid & 127;

    __shared__ float s[11 * C_];
    __shared__ float ys[4 * C_];

    for (int idx = tid; idx < 11 * C_; idx += 512)
        s[idx] = P[(size_t)a * 11 * C_ + idx] +
                 P[((size_t)(N_ + a) * 11) * C_ + idx];
    __syncthreads();

    {
        const int j = tid >> 7;
        float y;
        if (j == 0) {
            y = b0v[f];
            const float4* w = (const float4*)(w0 + (size_t)f * (2 * C_));
            const float* s0 = s + 0 * C_;
            const float* s7 = s + 7 * C_;
            for (int c4 = 0; c4 < C_ / 4; ++c4) {
                const float4 wa = w[c4];
                const float4 wb = w[C_ / 4 + c4];
                y = fmaf(wa.x, s0[c4 * 4 + 0], y);
                y = fmaf(wa.y, s0[c4 * 4 + 1], y);
                y = fmaf(wa.z, s0[c4 * 4 + 2], y);
                y = fmaf(wa.w, s0[c4 * 4 + 3], y);
                y = fmaf(wb.x, s7[c4 * 4 + 0], y);
                y = fmaf(wb.y, s7[c4 * 4 + 1], y);
                y = fmaf(wb.z, s7[c4 * 4 + 2], y);
                y = fmaf(wb.w, s7[c4 * 4 + 3], y);
            }
        } else {
            y = 0.f;
            const float4* w = (const float4*)(w1 + (size_t)f * (3 * C_));
            const float* sb = s + j * C_;
            const float* sa = s + (3 + j) * C_;
            const float* so = s + (7 + j) * C_;
            for (int c4 = 0; c4 < C_ / 4; ++c4) {
                const float4 w_b = w[c4];
                const float4 w_a = w[C_ / 4 + c4];
                const float4 w_o = w[2 * (C_ / 4) + c4];
                y = fmaf(w_b.x, sb[c4 * 4 + 0], y);
                y = fmaf(w_b.y, sb[c4 * 4 + 1], y);
                y = fmaf(w_b.z, sb[c4 * 4 + 2], y);
                y = fmaf(w_b.w, sb[c4 * 4 + 3], y);
                y = fmaf(w_a.x, sa[c4 * 4 + 0], y);
                y = fmaf(w_a.y, sa[c4 * 4 + 1], y);
                y = fmaf(w_a.z, sa[c4 * 4 + 2], y);
                y = fmaf(w_a.w, sa[c4 * 4 + 3], y);
                y = fmaf(w_o.x, so[c4 * 4 + 0], y);
                y = fmaf(w_o.y, so[c4 * 4 + 1], y);
                y = fmaf(w_o.z, so[c4 * 4 + 2], y);
                y = fmaf(w_o.w, so[c4 * 4 + 3], y);
            }
        }
        ys[j * C_ + f] = y;
    }
    __syncthreads();

    if (NONLIN) {
        if (tid < C_) {
            const float y0 = ys[tid];
            const float yx = ys[C_ + tid], yy = ys[2 * C_ + tid], yz = ys[3 * C_ + tid];
            const float x0v = y0 > 0.f ? y0 : expm1f(y0);
            const float nsq = fmaf(yx, yx, fmaf(yy, yy, yz * yz));
            const float nn  = sqrtf(fmaxf(nsq, 1e-12f));
            const float g   = nlb[tid] + nn;
            const float sc  = (g > 0.f ? g : expm1f(g)) / nn;
            uint2 w;
            *(__half2*)&w.x = __floats2half2_rn(x0v, yx * sc);
            *(__half2*)&w.y = __floats2half2_rn(yy * sc, yz * sc);
            xout[(size_t)a * C_ + tid] = w;
        }
    }
    if (LAST) {
        if (tid < C_) {
            const float y0 = ys[tid];
            const float yx = ys[C_ + tid], yy = ys[2 * C_ + tid], yz = ys[3 * C_ + tid];
            out[a * C_ + tid] = y0;                   // x0 [N,C,1]
            float* o1 = out + N_ * C_;                // x1 [N,C,3]
            o1[a * (C_ * 3) + tid * 3 + 0] = yx;
            o1[a * (C_ * 3) + tid * 3 + 1] = yy;
            o1[a * (C_ * 3) + tid * 3 + 2] = yz;
        }
        __syncthreads();
        if (tid < 8) {                                // atom head from ys[0..127]
            float acc = predb[tid];
            for (int c = 0; c < C_; ++c)
                acc = fmaf(predW[tid * C_ + c], ys[c], acc);
            out[N_ * C_ + N_ * C_ * 3 + a * 8 + tid] = acc;
        }
    }
}

// ---------------------------------------------------------------------------
extern "C" void kernel_launch(void* const* d_in, const int* in_sizes, int n_in,
                              void* d_out, int out_size, void* d_ws, size_t ws_size,
                              hipStream_t stream)
{
    const float* r       = (const float*)d_in[0];
    const float* onehot  = (const float*)d_in[1];
    const float* embed_W = (const float*)d_in[2];
    const float* embed_b = (const float*)d_in[3];
    const float* Rw1     = (const float*)d_in[4];
    const float* Rb1     = (const float*)d_in[5];
    const float* Rw2     = (const float*)d_in[6];
    const float* Rb2     = (const float*)d_in[7];
    const float* si0_w0  = (const float*)d_in[8];
    const float* si0_b0  = (const float*)d_in[9];
    const float* si0_w1  = (const float*)d_in[10];
    const float* si1_w0  = (const float*)d_in[11];
    const float* si1_b0  = (const float*)d_in[12];
    const float* si1_w1  = (const float*)d_in[13];
    const float* si2_w0  = (const float*)d_in[14];
    const float* si2_b0  = (const float*)d_in[15];
    const float* si2_w1  = (const float*)d_in[16];
    const float* nl_b0   = (const float*)d_in[17];
    const float* nl_b1   = (const float*)d_in[18];
    const float* pred_W  = (const float*)d_in[19];
    const float* pred_b  = (const float*)d_in[20];
    (void)in_sizes; (void)n_in; (void)out_size; (void)ws_size;

    const float delta = DMAX_ / (float)(M_ - 1);

    // workspace layout (bytes):
    //   tab : M*12*C half2          = 1,966,080
    //   e   : N*C f32               =   393,216
    //   xa  : N*C uint2 (fp16 x4)   =   786,432
    //   xb  : N*C uint2             =   786,432
    //   P   : 2*N*11*C f32          = 8,650,752   (layer0 uses first 4 k's)
    // total ~12.6 MB (round 1 proved >=16.1 MB available)
    char* wsb = (char*)d_ws;
    __half2* table = (__half2*)wsb;
    float*   e     = (float*)(wsb + 1966080);
    uint2*   xa    = (uint2*)(wsb + 1966080 + 393216);
    uint2*   xb    = (uint2*)(wsb + 1966080 + 393216 + 786432);
    float*   P     = (float*)(wsb + 1966080 + 393216 + 786432 * 2);

    float* out = (float*)d_out;

    build_table_kernel<<<M_ / 4, 256, 0, stream>>>(Rw1, Rb1, Rw2, Rb2, table, delta);
    embed_kernel<<<(N_ * C_) / 256, 256, 0, stream>>>(onehot, embed_W, embed_b, e);

    // layer 0
    pair0_kernel<<<2 * N_, 256, 0, stream>>>(r, e, table, P);
    finish0_kernel<<<N_, 512, 0, stream>>>(P, si0_w0, si0_b0, si0_w1, nl_b0, xa);

    // layer 1
    pairF_kernel<2><<<2 * N_, 256, 0, stream>>>(r, xa, table, P);
    finishF_kernel<true, false><<<N_, 512, 0, stream>>>(
        P, si1_w0, si1_b0, si1_w1, nl_b1, xb, nullptr, nullptr, nullptr);

    // layer 2 (last)
    pairF_kernel<7><<<2 * N_, 256, 0, stream>>>(r, xb, table, P);
    finishF_kernel<false, true><<<N_, 512, 0, stream>>>(
        P, si2_w0, si2_b0, si2_w1, nullptr, nullptr, out, pred_W, pred_b);
}